// Round 4
// baseline (411.119 us; speedup 1.0000x reference)
//
#include <hip/hip_runtime.h>
#include <math.h>

// ---------------------------------------------------------------------------
// AdaptiveWindowAttention — round 9: gemm_qkv ported to the m201 geometry:
// 256x256 tile, BK=64, 512 thr / 8 waves (2M x 4N), per-wave 128x64,
// k-half-plane LDS (4 planes x 32KB = 128KB), 4 phases/tile with counted
// vmcnt(8) (never 0 in main loop), setprio around MFMA, XCD-swizzled grid.
// gemm_out stays on the proven 128^2 core. attn keeps per-wave tile bounds.
// B=2 S=2048 EMB=2048 H=16 D=128; window in [64,256]
// ---------------------------------------------------------------------------

#define S_LEN 2048
#define EMB 2048
#define HEADS 16
#define HDIM 128
#define NT 20          // attn: 320-key span = NT*16
#define PSTR 336       // attn: P row stride in f16 (320 + 16 pad)

typedef _Float16 f16x8 __attribute__((ext_vector_type(8)));
typedef _Float16 f16x4 __attribute__((ext_vector_type(4)));
typedef float f32x4 __attribute__((ext_vector_type(4)));

__device__ __forceinline__ void gld16(const void* g, void* l) {
    __builtin_amdgcn_global_load_lds(
        (const __attribute__((address_space(1))) unsigned int*)g,
        (__attribute__((address_space(3))) unsigned int*)l, 16, 0, 0);
}

// ---------------- rope tables (cos,sin interleaved) ----------------
__global__ void rope_table(float2* __restrict__ cstab) {
    int s = blockIdx.x;
    int d = threadIdx.x;
    int j = d & 63;
    double inv = pow(10000.0, -(double)j / 64.0);
    double ang = (double)s * inv;
    cstab[s * HDIM + d] = make_float2((float)cos(ang), (float)sin(ang));
}

// ---------------- batch stats + fused x->f16 (float4, 4 cols/thread) --------
__global__ __launch_bounds__(256) void col_reduce(const float* __restrict__ x,
                                                  float* __restrict__ xmean_acc,
                                                  double* __restrict__ scal,
                                                  _Float16* __restrict__ x16) {
    int b = blockIdx.z;
    int cg = blockIdx.x;     // 2 column groups of 1024
    int sg = blockIdx.y;     // 64 row chunks of 32
    int e4 = cg * 256 + threadIdx.x;          // float4 column index
    const size_t base = ((size_t)b * S_LEN + sg * 32) * EMB;
    const float4* xb = (const float4*)(x + base) + e4;
    f16x4* xo = (f16x4*)(x16 + base) + e4;
    double cs0 = 0.0, cs1 = 0.0, cs2 = 0.0, cs3 = 0.0;
    double cq = 0.0;
    for (int s = 0; s < 32; ++s) {
        float4 v = xb[(size_t)s * (EMB / 4)];
        f16x4 o;
        o.x = (_Float16)v.x; o.y = (_Float16)v.y;
        o.z = (_Float16)v.z; o.w = (_Float16)v.w;
        xo[(size_t)s * (EMB / 4)] = o;
        cs0 += v.x; cs1 += v.y; cs2 += v.z; cs3 += v.w;
        cq += (double)v.x * v.x + (double)v.y * v.y +
              (double)v.z * v.z + (double)v.w * v.w;
    }
    float* xm = xmean_acc + b * EMB + e4 * 4;
    atomicAdd(xm + 0, (float)cs0);
    atomicAdd(xm + 1, (float)cs1);
    atomicAdd(xm + 2, (float)cs2);
    atomicAdd(xm + 3, (float)cs3);
    __shared__ double rs[256], rq[256];
    rs[threadIdx.x] = cs0 + cs1 + cs2 + cs3;
    rq[threadIdx.x] = cq;
    __syncthreads();
    for (int off = 128; off > 0; off >>= 1) {
        if (threadIdx.x < off) {
            rs[threadIdx.x] += rs[threadIdx.x + off];
            rq[threadIdx.x] += rq[threadIdx.x + off];
        }
        __syncthreads();
    }
    if (threadIdx.x == 0) {
        atomicAdd(&scal[b], rs[0]);
        atomicAdd(&scal[2 + b], rq[0]);
    }
}

__global__ __launch_bounds__(256) void hidden_kernel(const float* __restrict__ xmean_acc,
                                                     const float* __restrict__ wc1,
                                                     float* __restrict__ hidden) {
    int j = blockIdx.x;
    int b = blockIdx.y;
    const float* xm = xmean_acc + b * EMB;
    const float* wr = wc1 + (size_t)j * EMB;
    double acc = 0.0;
    for (int k = threadIdx.x; k < EMB; k += 256)
        acc += (double)xm[k] * (double)wr[k];
    __shared__ double red[256];
    red[threadIdx.x] = acc;
    __syncthreads();
    for (int off = 128; off > 0; off >>= 1) {
        if (threadIdx.x < off) red[threadIdx.x] += red[threadIdx.x + off];
        __syncthreads();
    }
    if (threadIdx.x == 0) {
        double z = red[0] * (1.0 / 2048.0);
        hidden[b * 512 + j] = (float)(z / (1.0 + exp(-z)));
    }
}

__global__ __launch_bounds__(512) void window_kernel(const float* __restrict__ hidden,
                                                     const float* __restrict__ wc2,
                                                     const double* __restrict__ scal,
                                                     int* __restrict__ wout) {
    __shared__ double red[512];
    __shared__ double wfs[2];
    for (int b = 0; b < 2; ++b) {
        red[threadIdx.x] = (double)hidden[b * 512 + threadIdx.x] * (double)wc2[threadIdx.x];
        __syncthreads();
        for (int off = 256; off > 0; off >>= 1) {
            if (threadIdx.x < off) red[threadIdx.x] += red[threadIdx.x + off];
            __syncthreads();
        }
        if (threadIdx.x == 0) {
            double pre = red[0];
            double learned = 1.0 / (1.0 + exp(-pre));
            const double N = (double)S_LEN * (double)EMB;
            double sum = scal[b], sq = scal[2 + b];
            double var = (sq - sum * sum / N) / (N - 1.0);
            double vn = 1.0 / (1.0 + exp(-(var * 10.0 - 5.0)));
            double comp = 0.5 * (vn + learned);
            wfs[b] = 64.0 + comp * 192.0;
        }
        __syncthreads();
    }
    if (threadIdx.x == 0) {
        float wf = (float)(0.5 * (wfs[0] + wfs[1]));
        int w = (int)wf;
        if (w > S_LEN) w = S_LEN;
        if (w < 64) w = 64;
        *wout = w;
    }
}

// ---------------- f32 -> f16 conversion (both weights, one launch) ----------
#define NQKV4 3145728   // 3*2048*2048/4
#define NOUT4 1048576   // 2048*2048/4
__global__ __launch_bounds__(256) void cvt_weights(const float* __restrict__ wqkv,
                                                   const float* __restrict__ wout,
                                                   _Float16* __restrict__ d_qkv,
                                                   _Float16* __restrict__ d_out) {
    int i = blockIdx.x * 256 + threadIdx.x;
    const float4* s;
    f16x4* d;
    if (i < NQKV4) {
        s = (const float4*)wqkv + i;
        d = (f16x4*)d_qkv + i;
    } else {
        s = (const float4*)wout + (i - NQKV4);
        d = (f16x4*)d_out + (i - NQKV4);
    }
    float4 v = *s;
    f16x4 o;
    o.x = (_Float16)v.x; o.y = (_Float16)v.y;
    o.z = (_Float16)v.z; o.w = (_Float16)v.w;
    *d = o;
}

// ---------------------------------------------------------------------------
// 256^2 deep-pipelined GEMM for qkv. 512 thr = 8 waves (wm=wv>>2, wn=wv&3);
// per-wave C = 128x64 (acc[8][4]). LDS planes Ap/Bp[buf][ks]: 256 rows x 32 k.
// Ring: tile u phases stage  ph1:A(u+1,ks1) ph2:B(u+1,ks1) ph3:A(u+2,ks0)
// ph4:B(u+2,ks0); every staged quarter lands >=2 phases before first read,
// enforced by vmcnt(8) at ph2/ph4 ends + trailing barrier. Never vmcnt(0)
// in the main loop.
// ---------------------------------------------------------------------------

#define STG_A(bufc, ksc, kofs)                                              \
    gld16(aSrc + (kofs), &Ap[bufc][ksc][wv * 512]);                         \
    gld16(aSrc + (kofs) + (size_t)128 * EMB, &Ap[bufc][ksc][4096 + wv * 512]);
#define STG_B(bufc, ksc, kofs)                                              \
    gld16(bSrc + (kofs), &Bp[bufc][ksc][wv * 512]);                         \
    gld16(bSrc + (kofs) + (size_t)128 * EMB, &Bp[bufc][ksc][4096 + wv * 512]);

#define VM8 asm volatile("s_waitcnt vmcnt(8)" ::: "memory");
#define VM4 asm volatile("s_waitcnt vmcnt(4)" ::: "memory");
#define VM0 asm volatile("s_waitcnt vmcnt(0)" ::: "memory");
#define VMN

// phase A: loads B-frags (register-carried into the following QPH_B) + A mh0
#define QPH_A(bufc, ksc, VM, ...)                                           \
    {                                                                       \
        f16x8 af[4];                                                        \
        _Pragma("unroll")                                                   \
        for (int j_ = 0; j_ < 4; ++j_)                                      \
            bf[j_] = *(const f16x8*)&Bp[bufc][ksc][boff0 + j_ * 512];       \
        _Pragma("unroll")                                                   \
        for (int i_ = 0; i_ < 4; ++i_)                                      \
            af[i_] = *(const f16x8*)&Ap[bufc][ksc][aoff0 + i_ * 512];       \
        __VA_ARGS__                                                         \
        __builtin_amdgcn_sched_barrier(0);                                  \
        __builtin_amdgcn_s_barrier();                                       \
        asm volatile("s_waitcnt lgkmcnt(0)" ::: "memory");                  \
        __builtin_amdgcn_sched_barrier(0);                                  \
        __builtin_amdgcn_s_setprio(1);                                      \
        _Pragma("unroll")                                                   \
        for (int i_ = 0; i_ < 4; ++i_)                                      \
            _Pragma("unroll")                                               \
            for (int j_ = 0; j_ < 4; ++j_)                                  \
                acc[i_][j_] = __builtin_amdgcn_mfma_f32_16x16x32_f16(       \
                    af[i_], bf[j_], acc[i_][j_], 0, 0, 0);                  \
        __builtin_amdgcn_s_setprio(0);                                      \
        __builtin_amdgcn_sched_barrier(0);                                  \
        VM                                                                  \
        __builtin_amdgcn_s_barrier();                                       \
        __builtin_amdgcn_sched_barrier(0);                                  \
    }

// phase B: A mh1 only; reuses bf
#define QPH_B(bufc, ksc, VM, ...)                                           \
    {                                                                       \
        f16x8 af[4];                                                        \
        _Pragma("unroll")                                                   \
        for (int i_ = 0; i_ < 4; ++i_)                                      \
            af[i_] = *(const f16x8*)&Ap[bufc][ksc][aoff0 + 2048 + i_ * 512];\
        __VA_ARGS__                                                         \
        __builtin_amdgcn_sched_barrier(0);                                  \
        __builtin_amdgcn_s_barrier();                                       \
        asm volatile("s_waitcnt lgkmcnt(0)" ::: "memory");                  \
        __builtin_amdgcn_sched_barrier(0);                                  \
        __builtin_amdgcn_s_setprio(1);                                      \
        _Pragma("unroll")                                                   \
        for (int i_ = 0; i_ < 4; ++i_)                                      \
            _Pragma("unroll")                                               \
            for (int j_ = 0; j_ < 4; ++j_)                                  \
                acc[4 + i_][j_] = __builtin_amdgcn_mfma_f32_16x16x32_f16(   \
                    af[i_], bf[j_], acc[4 + i_][j_], 0, 0, 0);              \
        __builtin_amdgcn_s_setprio(0);                                      \
        __builtin_amdgcn_sched_barrier(0);                                  \
        VM                                                                  \
        __builtin_amdgcn_s_barrier();                                       \
        __builtin_amdgcn_sched_barrier(0);                                  \
    }

__global__ __launch_bounds__(512, 2) void gemm_qkv_f16(const _Float16* __restrict__ An,
                                                       const _Float16* __restrict__ Wn,
                                                       _Float16* __restrict__ q16,
                                                       _Float16* __restrict__ k16,
                                                       _Float16* __restrict__ vt,
                                                       const float2* __restrict__ cstab) {
    __shared__ __align__(16) _Float16 Ap[2][2][8192];   // [buf][ks][256*32]
    __shared__ __align__(16) _Float16 Bp[2][2][8192];
    const int tid = threadIdx.x;
    const int lane = tid & 63;
    const int wv = tid >> 6;
    const int wm = wv >> 2;        // 0..1
    const int wn = wv & 3;         // 0..3
    // XCD-aware bijective swizzle (384 blocks, 384 % 8 == 0)
    const int f = blockIdx.y * 24 + blockIdx.x;
    const int fs = (f & 7) * 48 + (f >> 3);
    const int m0 = (fs / 24) * 256;
    const int n0 = (fs % 24) * 256;
    // staging source (plain row-major; 64B-row planes are b128-floor-optimal)
    const int srow = tid >> 2;               // 0..127
    const int schk = tid & 3;
    const _Float16* aSrc = An + (size_t)(m0 + srow) * EMB + schk * 8;
    const _Float16* bSrc = Wn + (size_t)(n0 + srow) * EMB + schk * 8;
    // fragment read offsets (f16 units within a 256x32 plane)
    const int frow = lane & 15;
    const int fgrp = lane >> 4;
    const int aoff0 = (wm * 128 + frow) * 32 + fgrp * 8;
    const int boff0 = (wn * 64 + frow) * 32 + fgrp * 8;
    f32x4 acc[8][4] = {};
    f16x8 bf[4];

    // prologue: stage P(0,ks0), P(0,ks1), P(1,ks0); first quarter must land
    STG_A(0, 0, 0) STG_B(0, 0, 0)
    STG_A(0, 1, 32) STG_B(0, 1, 32)
    STG_A(1, 0, 64) STG_B(1, 0, 64)
    VM8
    __builtin_amdgcn_s_barrier();
    __builtin_amdgcn_sched_barrier(0);

    // main: 15 iters x 2 tiles (0..29), stages through P(31,ks0)
    for (int it = 0; it < 15; ++it) {
        QPH_A(0, 0, VMN, STG_A(1, 1, 96))
        QPH_B(0, 0, VM8, STG_B(1, 1, 96))
        QPH_A(0, 1, VMN, STG_A(0, 0, 128))
        QPH_B(0, 1, VM8, STG_B(0, 0, 128))
        QPH_A(1, 0, VMN, STG_A(0, 1, 160))
        QPH_B(1, 0, VM8, STG_B(0, 1, 160))
        QPH_A(1, 1, VMN, STG_A(1, 0, 192))
        QPH_B(1, 1, VM8, STG_B(1, 0, 192))
        aSrc += 128;
        bSrc += 128;
    }
    // tile 30 (buf0): stage P(31,ks1) then drain to 4
    QPH_A(0, 0, VMN, STG_A(1, 1, 96))
    QPH_B(0, 0, VM8, STG_B(1, 1, 96))
    QPH_A(0, 1, VMN)
    QPH_B(0, 1, VM4)
    // tile 31 (buf1): no stages
    QPH_A(1, 0, VMN)
    QPH_B(1, 0, VM0)
    QPH_A(1, 1, VMN)
    QPH_B(1, 1, VMN)

    // ---- epilogue: rope fused q/k; v transposed ----
    const int colbase = lane & 15;
    const int rowoff = fgrp * 4;
    const int nb = n0 + wn * 64;
    const int which = nb >> 11;
    const int h = (nb >> 7) & 15;
    const int d0 = nb & 127;               // 0 or 64
    if (which == 2) {
#pragma unroll
        for (int i = 0; i < 8; ++i) {
#pragma unroll
            for (int j = 0; j < 4; ++j) {
                const int d = d0 + j * 16 + colbase;
                int m = m0 + wm * 128 + i * 16 + rowoff;  // 4 consecutive rows
                int b = m >> 11, s = m & 2047;
                f16x4 o;
#pragma unroll
                for (int r = 0; r < 4; ++r) o[r] = (_Float16)acc[i][j][r];
                *(f16x4*)&vt[(((size_t)b * HEADS + h) * HDIM + d) * S_LEN + s] = o;
            }
        }
    } else {
        _Float16* dst = which == 0 ? q16 : k16;
        const float sgn = (colbase & 1) ? 1.f : -1.f;   // rotate_half sign
#pragma unroll
        for (int i = 0; i < 8; ++i) {
#pragma unroll
            for (int j = 0; j < 4; ++j) {
                const int d = d0 + j * 16 + colbase;
#pragma unroll
                for (int r = 0; r < 4; ++r) {
                    int m = m0 + wm * 128 + i * 16 + rowoff + r;
                    int b = m >> 11, s = m & 2047;
                    float a = acc[i][j][r];
                    float p = __shfl_xor(a, 1, 64);      // partner: d^1, same s
                    float2 cs = cstab[(size_t)s * HDIM + d];
                    float o = fmaf(a, cs.x, sgn * p * cs.y);
                    dst[(((size_t)b * HEADS + h) * S_LEN + s) * HDIM + d] = (_Float16)o;
                }
            }
        }
    }
}

// ---------------- 128^2 GEMM core (proven round-6) for gemm_out -------------
#define GEMM_PROLOGUE(An, Wn)                                                   \
    __shared__ _Float16 As[128 * 64];                                           \
    __shared__ _Float16 Bs[128 * 64];                                           \
    const int tid = threadIdx.x;                                                \
    const int lane = tid & 63;                                                  \
    const int wv = tid >> 6;                                                    \
    const int wm = wv >> 1, wn = wv & 1;                                        \
    const int m0 = blockIdx.y * 128;                                            \
    const int n0 = blockIdx.x * 128;                                            \
    const int lrow = lane >> 3;                            /* 0..7 */           \
    const int lchk = (lane & 7) ^ lrow;                    /* swizzled src */   \
    const int srow = wv * 32 + lrow;                                            \
    const _Float16* agp = An + (size_t)(m0 + srow) * EMB + lchk * 8;            \
    const _Float16* bgp = Wn + (size_t)(n0 + srow) * EMB + lchk * 8;            \
    _Float16* al = &As[wv * 32 * 64];                                           \
    _Float16* bl = &Bs[wv * 32 * 64];                                           \
    const int frow = lane & 15;                                                 \
    const int fgrp = lane >> 4;                                                 \
    f32x4 acc[4][4] = {};                                                       \
    for (int k0 = 0; k0 < EMB; k0 += 64) {                                      \
        __syncthreads();                                                        \
        _Pragma("unroll")                                                       \
        for (int t = 0; t < 4; ++t) {                                           \
            gld16(agp + (size_t)t * 8 * EMB, al + t * 8 * 64);                  \
            gld16(bgp + (size_t)t * 8 * EMB, bl + t * 8 * 64);                  \
        }                                                                       \
        agp += 64; bgp += 64;                                                   \
        __syncthreads();                                                        \
        _Pragma("unroll")                                                       \
        for (int ks = 0; ks < 2; ++ks) {                                        \
            f16x8 af[4], bf[4];                                                 \
            _Pragma("unroll")                                                   \
            for (int i = 0; i < 4; ++i)                                         \
                af[i] = *(const f16x8*)&As[(wm * 64 + i * 16 + frow) * 64 +     \
                                           (((ks * 4 + fgrp) ^ (frow & 7)) * 8)]; \
            _Pragma("unroll")                                                   \
            for (int j = 0; j < 4; ++j)                                         \
                bf[j] = *(const f16x8*)&Bs[(wn * 64 + j * 16 + frow) * 64 +     \
                                           (((ks * 4 + fgrp) ^ (frow & 7)) * 8)]; \
            _Pragma("unroll")                                                   \
            for (int i = 0; i < 4; ++i)                                         \
                _Pragma("unroll")                                               \
                for (int j = 0; j < 4; ++j)                                     \
                    acc[i][j] = __builtin_amdgcn_mfma_f32_16x16x32_f16(         \
                        af[i], bf[j], acc[i][j], 0, 0, 0);                      \
        }                                                                       \
    }                                                                           \
    const int colbase = lane & 15;                                              \
    const int rowoff = (lane >> 4) * 4;

__global__ __launch_bounds__(256) void gemm_out_f16(const _Float16* __restrict__ An,
                                                    const _Float16* __restrict__ Wn,
                                                    float* __restrict__ C) {
    GEMM_PROLOGUE(An, Wn)
#pragma unroll
    for (int i = 0; i < 4; ++i) {
#pragma unroll
        for (int j = 0; j < 4; ++j) {
            const int n = n0 + wn * 64 + j * 16 + colbase;
#pragma unroll
            for (int r = 0; r < 4; ++r) {
                int m = m0 + wm * 64 + i * 16 + rowoff + r;
                C[(size_t)m * EMB + n] = acc[i][j][r];
            }
        }
    }
}

// ---------------- MFMA attention (per-wave exact tile bounds) ----------------
__global__ __launch_bounds__(256) void attn_mfma(const _Float16* __restrict__ q16,
                                                 const _Float16* __restrict__ k16,
                                                 const _Float16* __restrict__ v16t,
                                                 _Float16* __restrict__ ob,
                                                 const int* __restrict__ wptr) {
    const int q0 = blockIdx.x * 64;
    const int h = blockIdx.y;
    const int b = blockIdx.z;
    const int tid = threadIdx.x;
    const int lane = tid & 63;
    const int wv = tid >> 6;
    const int w = *wptr;

    __shared__ _Float16 Pl[4][16 * PSTR];
    _Float16* Pw = Pl[wv];

    const int kstart = q0 - 256;
    int ntlo_w = ((257 - w) >> 4) + wv;
    int ntlo_n = q0 < 256 ? ((256 - q0) >> 4) : 0;
    const int lo = ntlo_w > ntlo_n ? ntlo_w : ntlo_n;
    const int hi = wv + 17;
    const int pvlo = lo >> 1;
    const int pvhi = (hi + 1) >> 1;
    const int plo2 = pvlo << 1;
    const int phi2 = pvhi << 1;

    const int frow = lane & 15;
    const int fgrp = lane >> 4;
    const int fcol = fgrp * 8;

    const size_t bh = (size_t)b * HEADS + h;
    const _Float16* Qp = q16 + (bh * S_LEN + q0 + wv * 16 + frow) * HDIM + fcol;
    const _Float16* Kb = k16 + bh * S_LEN * HDIM;
    const _Float16* Vt = v16t + bh * HDIM * S_LEN;

    f16x8 aq[4];
#pragma unroll
    for (int ks = 0; ks < 4; ++ks) aq[ks] = *(const f16x8*)(Qp + ks * 32);

    // ---- QK^T (only alive tiles) ----
    f32x4 accs[NT];
#pragma unroll
    for (int nt = 0; nt < NT; ++nt) accs[nt] = (f32x4){0.f, 0.f, 0.f, 0.f};
#pragma unroll
    for (int nt = 0; nt < NT; ++nt) {
        if (nt < lo || nt >= hi) continue;
        int krow = kstart + nt * 16 + frow;
        if (krow < 0) krow = 0;
        const _Float16* kp = Kb + (size_t)krow * HDIM + fcol;
#pragma unroll
        for (int ks = 0; ks < 4; ++ks) {
            f16x8 bk = *(const f16x8*)(kp + ks * 32);
            accs[nt] = __builtin_amdgcn_mfma_f32_16x16x32_f16(aq[ks], bk, accs[nt], 0, 0, 0);
        }
    }

    // ---- mask + scale; row max ----
    const int qrow = fgrp * 4;
    const int qabs = q0 + wv * 16 + qrow;
    const float scale = 0.08838834764831845f;
    float mx[4] = {-INFINITY, -INFINITY, -INFINITY, -INFINITY};
#pragma unroll
    for (int nt = 0; nt < NT; ++nt) {
        if (nt < lo || nt >= hi) continue;
        int key = kstart + nt * 16 + frow;
#pragma unroll
        for (int r = 0; r < 4; ++r) {
            int rel = (qabs + r) - key;
            bool keep = (key >= 0) && (rel >= 0) && (rel < w);
            float s = keep ? accs[nt][r] * scale : -INFINITY;
            accs[nt][r] = s;
            mx[r] = fmaxf(mx[r], s);
        }
    }
#pragma unroll
    for (int r = 0; r < 4; ++r) {
        float m = mx[r];
#pragma unroll
        for (int off = 1; off < 16; off <<= 1)
            m = fmaxf(m, __shfl_xor(m, off, 64));
        mx[r] = m;
    }

    // ---- exp, row sum, store P (zero-fill dead tiles within PV span) ----
    float ls[4] = {0.f, 0.f, 0.f, 0.f};
#pragma unroll
    for (int nt = 0; nt < NT; ++nt) {
        if (nt < plo2 || nt >= phi2) continue;
        const bool alive = (nt >= lo) && (nt < hi);
#pragma unroll
        for (int r = 0; r < 4; ++r) {
            float p = alive ? __expf(accs[nt][r] - mx[r]) : 0.f;
            ls[r] += p;
            Pw[(qrow + r) * PSTR + nt * 16 + frow] = (_Float16)p;
        }
    }
    float inv[4];
#pragma unroll
    for (int r = 0; r < 4; ++r) {
        float l = ls[r];
#pragma unroll
        for (int off = 1; off < 16; off <<= 1)
            l += __shfl_xor(l, off, 64);
        inv[r] = 1.f / l;
    }

    // ---- PV (only alive 32-key tiles) ----
    f32x4 acco[8];
#pragma unroll
    for (int jt = 0; jt < 8; ++jt) acco[jt] = (f32x4){0.f, 0.f, 0.f, 0.f};
    const _Float16* Pr = &Pl[wv][frow * PSTR];
#pragma unroll
    for (int kp = 0; kp < 10; ++kp) {
        if (kp < pvlo || kp >= pvhi) continue;
        f16x8 ap = *(const f16x8*)(Pr + kp * 32 + fcol);
        int kv = kstart + kp * 32 + fcol;
        if (kv < 0) kv = 0;
#pragma unroll
        for (int jt = 0; jt < 8; ++jt) {
            f16x8 bv = *(const f16x8*)(Vt + (size_t)(jt * 16 + frow) * S_LEN + kv);
            acco[jt] = __builtin_amdgcn_mfma_f32_16x16x32_f16(ap, bv, acco[jt], 0, 0, 0);
        }
    }

    // ---- store O (b, s, h*128+d) f16 ----
#pragma unroll
    for (int jt = 0; jt < 8; ++jt) {
#pragma unroll
        for (int r = 0; r < 4; ++r) {
            int s = qabs + r;
            ob[((size_t)b * S_LEN + s) * EMB + h * HDIM + jt * 16 + frow] =
                (_Float16)(acco[jt][r] * inv[r]);
        }
    }
}

// ---------------------------------------------------------------------------
extern "C" void kernel_launch(void* const* d_in, const int* in_sizes, int n_in,
                              void* d_out, int out_size, void* d_ws, size_t ws_size,
                              hipStream_t stream) {
    const float* x     = (const float*)d_in[0];
    const float* w_qkv = (const float*)d_in[1];
    const float* w_out = (const float*)d_in[2];
    const float* w_c1  = (const float*)d_in[3];
    const float* w_c2  = (const float*)d_in[4];
    float* out = (float*)d_out;
    char* ws = (char*)d_ws;

    // ws layout (bytes). ao16 aliases wqkv16 (dead after gemm_qkv).
    double*    scal   = (double*)(ws + 0);
    int*       win    = (int*)(ws + 64);
    float*     xmean  = (float*)(ws + 128);
    float*     hidden = (float*)(ws + 16640);
    float2*    cstab  = (float2*)(ws + 32768);       // 2 MB
    _Float16*  x16    = (_Float16*)(ws + 4194304);   // 16.8 MB
    _Float16*  wqkv16 = (_Float16*)(ws + 20971520);  // 25.2 MB
    _Float16*  ao16   = (_Float16*)(ws + 20971520);  // alias
    _Float16*  v16t   = (_Float16*)(ws + 46137344);  // 16.8 MB
    _Float16*  q16    = (_Float16*)(ws + 62914560);  // 16.8 MB
    _Float16*  k16    = (_Float16*)(ws + 79691776);  // 16.8 MB
    _Float16*  wout16 = (_Float16*)(ws + 96468992);  // 8.4 MB

    hipMemsetAsync(d_ws, 0, 32768, stream);

    rope_table<<<dim3(S_LEN), dim3(HDIM), 0, stream>>>(cstab);
    col_reduce<<<dim3(2, 64, 2), dim3(256), 0, stream>>>(x, xmean, scal, x16);
    hidden_kernel<<<dim3(512, 2), dim3(256), 0, stream>>>(xmean, w_c1, hidden);
    window_kernel<<<dim3(1), dim3(512), 0, stream>>>(hidden, w_c2, scal, win);

    cvt_weights<<<dim3((NQKV4 + NOUT4) / 256), dim3(256), 0, stream>>>(
        w_qkv, w_out, wqkv16, wout16);

    gemm_qkv_f16<<<dim3(24, 16), dim3(512), 0, stream>>>(x16, wqkv16, q16, k16, v16t, cstab);
    attn_mfma<<<dim3(32, HEADS, 2), dim3(256), 0, stream>>>(q16, k16, v16t, ao16, win);
    gemm_out_f16<<<dim3(16, 32), dim3(256), 0, stream>>>(ao16, wout16, out);
}

// Round 5
// 396.376 us; speedup vs baseline: 1.0372x; 1.0372x over previous
//
#include <hip/hip_runtime.h>
#include <math.h>

// ---------------------------------------------------------------------------
// AdaptiveWindowAttention — round 10: proven 128^2 2-barrier GEMM core for
// both GEMMs (m97-structure; measured 128.7-137.5us for qkv) + bijective
// XCD-aware block swizzle on both GEMM grids (1536/512 blocks, both %8==0)
// to recover L2 locality (FETCH was 3x ideal). rope_table moved to f32
// (exp2f/sinf/cosf). attn keeps per-wave exact tile bounds (round-8, passed).
// Round-9 lesson: 32-k LDS planes => 8-way bank conflicts (9.4M) — conflict-
// free b128 requires the 128B-row XOR layout used here.
// B=2 S=2048 EMB=2048 H=16 D=128; window in [64,256]
// ---------------------------------------------------------------------------

#define S_LEN 2048
#define EMB 2048
#define HEADS 16
#define HDIM 128
#define NT 20          // attn: 320-key span = NT*16
#define PSTR 336       // attn: P row stride in f16 (320 + 16 pad)

typedef _Float16 f16x8 __attribute__((ext_vector_type(8)));
typedef _Float16 f16x4 __attribute__((ext_vector_type(4)));
typedef float f32x4 __attribute__((ext_vector_type(4)));

__device__ __forceinline__ void gld16(const void* g, void* l) {
    __builtin_amdgcn_global_load_lds(
        (const __attribute__((address_space(1))) unsigned int*)g,
        (__attribute__((address_space(3))) unsigned int*)l, 16, 0, 0);
}

// ---------------- rope tables (cos,sin interleaved), f32 ----------------
__global__ void rope_table(float2* __restrict__ cstab) {
    int s = blockIdx.x;
    int d = threadIdx.x;
    int j = d & 63;
    // 10000^(-j/64) = 2^(-log2(10000)*j/64)
    float inv = exp2f(-13.287712379549449f * (float)j * (1.0f / 64.0f));
    float ang = (float)s * inv;
    cstab[s * HDIM + d] = make_float2(cosf(ang), sinf(ang));
}

// ---------------- batch stats + fused x->f16 (float4, 4 cols/thread) --------
__global__ __launch_bounds__(256) void col_reduce(const float* __restrict__ x,
                                                  float* __restrict__ xmean_acc,
                                                  double* __restrict__ scal,
                                                  _Float16* __restrict__ x16) {
    int b = blockIdx.z;
    int cg = blockIdx.x;     // 2 column groups of 1024
    int sg = blockIdx.y;     // 64 row chunks of 32
    int e4 = cg * 256 + threadIdx.x;          // float4 column index
    const size_t base = ((size_t)b * S_LEN + sg * 32) * EMB;
    const float4* xb = (const float4*)(x + base) + e4;
    f16x4* xo = (f16x4*)(x16 + base) + e4;
    double cs0 = 0.0, cs1 = 0.0, cs2 = 0.0, cs3 = 0.0;
    double cq = 0.0;
    for (int s = 0; s < 32; ++s) {
        float4 v = xb[(size_t)s * (EMB / 4)];
        f16x4 o;
        o.x = (_Float16)v.x; o.y = (_Float16)v.y;
        o.z = (_Float16)v.z; o.w = (_Float16)v.w;
        xo[(size_t)s * (EMB / 4)] = o;
        cs0 += v.x; cs1 += v.y; cs2 += v.z; cs3 += v.w;
        cq += (double)v.x * v.x + (double)v.y * v.y +
              (double)v.z * v.z + (double)v.w * v.w;
    }
    float* xm = xmean_acc + b * EMB + e4 * 4;
    atomicAdd(xm + 0, (float)cs0);
    atomicAdd(xm + 1, (float)cs1);
    atomicAdd(xm + 2, (float)cs2);
    atomicAdd(xm + 3, (float)cs3);
    __shared__ double rs[256], rq[256];
    rs[threadIdx.x] = cs0 + cs1 + cs2 + cs3;
    rq[threadIdx.x] = cq;
    __syncthreads();
    for (int off = 128; off > 0; off >>= 1) {
        if (threadIdx.x < off) {
            rs[threadIdx.x] += rs[threadIdx.x + off];
            rq[threadIdx.x] += rq[threadIdx.x + off];
        }
        __syncthreads();
    }
    if (threadIdx.x == 0) {
        atomicAdd(&scal[b], rs[0]);
        atomicAdd(&scal[2 + b], rq[0]);
    }
}

__global__ __launch_bounds__(256) void hidden_kernel(const float* __restrict__ xmean_acc,
                                                     const float* __restrict__ wc1,
                                                     float* __restrict__ hidden) {
    int j = blockIdx.x;
    int b = blockIdx.y;
    const float* xm = xmean_acc + b * EMB;
    const float* wr = wc1 + (size_t)j * EMB;
    double acc = 0.0;
    for (int k = threadIdx.x; k < EMB; k += 256)
        acc += (double)xm[k] * (double)wr[k];
    __shared__ double red[256];
    red[threadIdx.x] = acc;
    __syncthreads();
    for (int off = 128; off > 0; off >>= 1) {
        if (threadIdx.x < off) red[threadIdx.x] += red[threadIdx.x + off];
        __syncthreads();
    }
    if (threadIdx.x == 0) {
        double z = red[0] * (1.0 / 2048.0);
        hidden[b * 512 + j] = (float)(z / (1.0 + exp(-z)));
    }
}

__global__ __launch_bounds__(512) void window_kernel(const float* __restrict__ hidden,
                                                     const float* __restrict__ wc2,
                                                     const double* __restrict__ scal,
                                                     int* __restrict__ wout) {
    __shared__ double red[512];
    __shared__ double wfs[2];
    for (int b = 0; b < 2; ++b) {
        red[threadIdx.x] = (double)hidden[b * 512 + threadIdx.x] * (double)wc2[threadIdx.x];
        __syncthreads();
        for (int off = 256; off > 0; off >>= 1) {
            if (threadIdx.x < off) red[threadIdx.x] += red[threadIdx.x + off];
            __syncthreads();
        }
        if (threadIdx.x == 0) {
            double pre = red[0];
            double learned = 1.0 / (1.0 + exp(-pre));
            const double N = (double)S_LEN * (double)EMB;
            double sum = scal[b], sq = scal[2 + b];
            double var = (sq - sum * sum / N) / (N - 1.0);
            double vn = 1.0 / (1.0 + exp(-(var * 10.0 - 5.0)));
            double comp = 0.5 * (vn + learned);
            wfs[b] = 64.0 + comp * 192.0;
        }
        __syncthreads();
    }
    if (threadIdx.x == 0) {
        float wf = (float)(0.5 * (wfs[0] + wfs[1]));
        int w = (int)wf;
        if (w > S_LEN) w = S_LEN;
        if (w < 64) w = 64;
        *wout = w;
    }
}

// ---------------- f32 -> f16 conversion (both weights, one launch) ----------
#define NQKV4 3145728   // 3*2048*2048/4
#define NOUT4 1048576   // 2048*2048/4
__global__ __launch_bounds__(256) void cvt_weights(const float* __restrict__ wqkv,
                                                   const float* __restrict__ wout,
                                                   _Float16* __restrict__ d_qkv,
                                                   _Float16* __restrict__ d_out) {
    int i = blockIdx.x * 256 + threadIdx.x;
    const float4* s;
    f16x4* d;
    if (i < NQKV4) {
        s = (const float4*)wqkv + i;
        d = (f16x4*)d_qkv + i;
    } else {
        s = (const float4*)wout + (i - NQKV4);
        d = (f16x4*)d_out + (i - NQKV4);
    }
    float4 v = *s;
    f16x4 o;
    o.x = (_Float16)v.x; o.y = (_Float16)v.y;
    o.z = (_Float16)v.z; o.w = (_Float16)v.w;
    *d = o;
}

// ---------------- MFMA GEMM core (BK=64, swizzled LDS, XCD-swizzled grid) ---
// Grid must have total blocks % 8 == 0 (1536 and 512 both qualify); the
// (f&7)*chunk + f>>3 remap is then bijective; blocks sharing an XCD walk n
// fastest so the A-panel (0.5 MB) stays L2-resident across its 48/16 reuses.
#define GEMM_PROLOGUE(An, Wn)                                                   \
    __shared__ _Float16 As[128 * 64];                                           \
    __shared__ _Float16 Bs[128 * 64];                                           \
    const int tid = threadIdx.x;                                                \
    const int lane = tid & 63;                                                  \
    const int wv = tid >> 6;                                                    \
    const int wm = wv >> 1, wn = wv & 1;                                        \
    const int nbx = gridDim.x;                                                  \
    const int f = blockIdx.y * nbx + blockIdx.x;                                \
    const int chunk = (nbx * gridDim.y) >> 3;                                   \
    const int fs = (f & 7) * chunk + (f >> 3);                                  \
    const int m0 = (fs / nbx) * 128;                                            \
    const int n0 = (fs % nbx) * 128;                                            \
    const int lrow = lane >> 3;                            /* 0..7 */           \
    const int lchk = (lane & 7) ^ lrow;                    /* swizzled src */   \
    const int srow = wv * 32 + lrow;                                            \
    const _Float16* agp = An + (size_t)(m0 + srow) * EMB + lchk * 8;            \
    const _Float16* bgp = Wn + (size_t)(n0 + srow) * EMB + lchk * 8;            \
    _Float16* al = &As[wv * 32 * 64];                                           \
    _Float16* bl = &Bs[wv * 32 * 64];                                           \
    const int frow = lane & 15;                                                 \
    const int fgrp = lane >> 4;                                                 \
    f32x4 acc[4][4] = {};                                                       \
    for (int k0 = 0; k0 < EMB; k0 += 64) {                                      \
        __syncthreads();                                                        \
        _Pragma("unroll")                                                       \
        for (int t = 0; t < 4; ++t) {                                           \
            gld16(agp + (size_t)t * 8 * EMB, al + t * 8 * 64);                  \
            gld16(bgp + (size_t)t * 8 * EMB, bl + t * 8 * 64);                  \
        }                                                                       \
        agp += 64; bgp += 64;                                                   \
        __syncthreads();                                                        \
        _Pragma("unroll")                                                       \
        for (int ks = 0; ks < 2; ++ks) {                                        \
            f16x8 af[4], bf[4];                                                 \
            _Pragma("unroll")                                                   \
            for (int i = 0; i < 4; ++i)                                         \
                af[i] = *(const f16x8*)&As[(wm * 64 + i * 16 + frow) * 64 +     \
                                           (((ks * 4 + fgrp) ^ (frow & 7)) * 8)]; \
            _Pragma("unroll")                                                   \
            for (int j = 0; j < 4; ++j)                                         \
                bf[j] = *(const f16x8*)&Bs[(wn * 64 + j * 16 + frow) * 64 +     \
                                           (((ks * 4 + fgrp) ^ (frow & 7)) * 8)]; \
            _Pragma("unroll")                                                   \
            for (int i = 0; i < 4; ++i)                                         \
                _Pragma("unroll")                                               \
                for (int j = 0; j < 4; ++j)                                     \
                    acc[i][j] = __builtin_amdgcn_mfma_f32_16x16x32_f16(         \
                        af[i], bf[j], acc[i][j], 0, 0, 0);                      \
        }                                                                       \
    }                                                                           \
    const int colbase = lane & 15;                                              \
    const int rowoff = (lane >> 4) * 4;

// qkv epilogue: rope fused -> q16/k16 f16 (B,H,S,D); v -> f16 (B,H,D,S)
__global__ __launch_bounds__(256) void gemm_qkv_f16(const _Float16* __restrict__ An,
                                                    const _Float16* __restrict__ Wn,
                                                    _Float16* __restrict__ q16,
                                                    _Float16* __restrict__ k16,
                                                    _Float16* __restrict__ vt,
                                                    const float2* __restrict__ cstab) {
    GEMM_PROLOGUE(An, Wn)
    const int which = n0 >> 11;
    const int h = (n0 >> 7) & 15;
    if (which == 2) {
#pragma unroll
        for (int i = 0; i < 4; ++i) {
#pragma unroll
            for (int j = 0; j < 4; ++j) {
                const int d = wn * 64 + j * 16 + colbase;
                int m = m0 + wm * 64 + i * 16 + rowoff;  // 4 consecutive rows
                int b = m >> 11, s = m & 2047;
                f16x4 o;
#pragma unroll
                for (int r = 0; r < 4; ++r) o[r] = (_Float16)acc[i][j][r];
                *(f16x4*)&vt[(((size_t)b * HEADS + h) * HDIM + d) * S_LEN + s] = o;
            }
        }
    } else {
        _Float16* dst = which == 0 ? q16 : k16;
        const float sgn = (colbase & 1) ? 1.f : -1.f;   // rotate_half sign
#pragma unroll
        for (int i = 0; i < 4; ++i) {
#pragma unroll
            for (int j = 0; j < 4; ++j) {
                const int d = wn * 64 + j * 16 + colbase;
#pragma unroll
                for (int r = 0; r < 4; ++r) {
                    int m = m0 + wm * 64 + i * 16 + rowoff + r;
                    int b = m >> 11, s = m & 2047;
                    float a = acc[i][j][r];
                    float p = __shfl_xor(a, 1, 64);      // partner: d^1, same s
                    float2 cs = cstab[(size_t)s * HDIM + d];
                    float o = fmaf(a, cs.x, sgn * p * cs.y);
                    dst[(((size_t)b * HEADS + h) * S_LEN + s) * HDIM + d] = (_Float16)o;
                }
            }
        }
    }
}

__global__ __launch_bounds__(256) void gemm_out_f16(const _Float16* __restrict__ An,
                                                    const _Float16* __restrict__ Wn,
                                                    float* __restrict__ C) {
    GEMM_PROLOGUE(An, Wn)
#pragma unroll
    for (int i = 0; i < 4; ++i) {
#pragma unroll
        for (int j = 0; j < 4; ++j) {
            const int n = n0 + wn * 64 + j * 16 + colbase;
#pragma unroll
            for (int r = 0; r < 4; ++r) {
                int m = m0 + wm * 64 + i * 16 + rowoff + r;
                C[(size_t)m * EMB + n] = acc[i][j][r];
            }
        }
    }
}

// ---------------- MFMA attention (per-wave exact tile bounds) ----------------
__global__ __launch_bounds__(256) void attn_mfma(const _Float16* __restrict__ q16,
                                                 const _Float16* __restrict__ k16,
                                                 const _Float16* __restrict__ v16t,
                                                 _Float16* __restrict__ ob,
                                                 const int* __restrict__ wptr) {
    const int q0 = blockIdx.x * 64;
    const int h = blockIdx.y;
    const int b = blockIdx.z;
    const int tid = threadIdx.x;
    const int lane = tid & 63;
    const int wv = tid >> 6;
    const int w = *wptr;

    __shared__ _Float16 Pl[4][16 * PSTR];
    _Float16* Pw = Pl[wv];

    const int kstart = q0 - 256;
    int ntlo_w = ((257 - w) >> 4) + wv;
    int ntlo_n = q0 < 256 ? ((256 - q0) >> 4) : 0;
    const int lo = ntlo_w > ntlo_n ? ntlo_w : ntlo_n;
    const int hi = wv + 17;
    const int pvlo = lo >> 1;
    const int pvhi = (hi + 1) >> 1;
    const int plo2 = pvlo << 1;
    const int phi2 = pvhi << 1;

    const int frow = lane & 15;
    const int fgrp = lane >> 4;
    const int fcol = fgrp * 8;

    const size_t bh = (size_t)b * HEADS + h;
    const _Float16* Qp = q16 + (bh * S_LEN + q0 + wv * 16 + frow) * HDIM + fcol;
    const _Float16* Kb = k16 + bh * S_LEN * HDIM;
    const _Float16* Vt = v16t + bh * HDIM * S_LEN;

    f16x8 aq[4];
#pragma unroll
    for (int ks = 0; ks < 4; ++ks) aq[ks] = *(const f16x8*)(Qp + ks * 32);

    // ---- QK^T (only alive tiles) ----
    f32x4 accs[NT];
#pragma unroll
    for (int nt = 0; nt < NT; ++nt) accs[nt] = (f32x4){0.f, 0.f, 0.f, 0.f};
#pragma unroll
    for (int nt = 0; nt < NT; ++nt) {
        if (nt < lo || nt >= hi) continue;
        int krow = kstart + nt * 16 + frow;
        if (krow < 0) krow = 0;
        const _Float16* kp = Kb + (size_t)krow * HDIM + fcol;
#pragma unroll
        for (int ks = 0; ks < 4; ++ks) {
            f16x8 bk = *(const f16x8*)(kp + ks * 32);
            accs[nt] = __builtin_amdgcn_mfma_f32_16x16x32_f16(aq[ks], bk, accs[nt], 0, 0, 0);
        }
    }

    // ---- mask + scale; row max ----
    const int qrow = fgrp * 4;
    const int qabs = q0 + wv * 16 + qrow;
    const float scale = 0.08838834764831845f;
    float mx[4] = {-INFINITY, -INFINITY, -INFINITY, -INFINITY};
#pragma unroll
    for (int nt = 0; nt < NT; ++nt) {
        if (nt < lo || nt >= hi) continue;
        int key = kstart + nt * 16 + frow;
#pragma unroll
        for (int r = 0; r < 4; ++r) {
            int rel = (qabs + r) - key;
            bool keep = (key >= 0) && (rel >= 0) && (rel < w);
            float s = keep ? accs[nt][r] * scale : -INFINITY;
            accs[nt][r] = s;
            mx[r] = fmaxf(mx[r], s);
        }
    }
#pragma unroll
    for (int r = 0; r < 4; ++r) {
        float m = mx[r];
#pragma unroll
        for (int off = 1; off < 16; off <<= 1)
            m = fmaxf(m, __shfl_xor(m, off, 64));
        mx[r] = m;
    }

    // ---- exp, row sum, store P (zero-fill dead tiles within PV span) ----
    float ls[4] = {0.f, 0.f, 0.f, 0.f};
#pragma unroll
    for (int nt = 0; nt < NT; ++nt) {
        if (nt < plo2 || nt >= phi2) continue;
        const bool alive = (nt >= lo) && (nt < hi);
#pragma unroll
        for (int r = 0; r < 4; ++r) {
            float p = alive ? __expf(accs[nt][r] - mx[r]) : 0.f;
            ls[r] += p;
            Pw[(qrow + r) * PSTR + nt * 16 + frow] = (_Float16)p;
        }
    }
    float inv[4];
#pragma unroll
    for (int r = 0; r < 4; ++r) {
        float l = ls[r];
#pragma unroll
        for (int off = 1; off < 16; off <<= 1)
            l += __shfl_xor(l, off, 64);
        inv[r] = 1.f / l;
    }

    // ---- PV (only alive 32-key tiles) ----
    f32x4 acco[8];
#pragma unroll
    for (int jt = 0; jt < 8; ++jt) acco[jt] = (f32x4){0.f, 0.f, 0.f, 0.f};
    const _Float16* Pr = &Pl[wv][frow * PSTR];
#pragma unroll
    for (int kp = 0; kp < 10; ++kp) {
        if (kp < pvlo || kp >= pvhi) continue;
        f16x8 ap = *(const f16x8*)(Pr + kp * 32 + fcol);
        int kv = kstart + kp * 32 + fcol;
        if (kv < 0) kv = 0;
#pragma unroll
        for (int jt = 0; jt < 8; ++jt) {
            f16x8 bv = *(const f16x8*)(Vt + (size_t)(jt * 16 + frow) * S_LEN + kv);
            acco[jt] = __builtin_amdgcn_mfma_f32_16x16x32_f16(ap, bv, acco[jt], 0, 0, 0);
        }
    }

    // ---- store O (b, s, h*128+d) f16 ----
#pragma unroll
    for (int jt = 0; jt < 8; ++jt) {
#pragma unroll
        for (int r = 0; r < 4; ++r) {
            int s = qabs + r;
            ob[((size_t)b * S_LEN + s) * EMB + h * HDIM + jt * 16 + frow] =
                (_Float16)(acco[jt][r] * inv[r]);
        }
    }
}

// ---------------------------------------------------------------------------
extern "C" void kernel_launch(void* const* d_in, const int* in_sizes, int n_in,
                              void* d_out, int out_size, void* d_ws, size_t ws_size,
                              hipStream_t stream) {
    const float* x     = (const float*)d_in[0];
    const float* w_qkv = (const float*)d_in[1];
    const float* w_out = (const float*)d_in[2];
    const float* w_c1  = (const float*)d_in[3];
    const float* w_c2  = (const float*)d_in[4];
    float* out = (float*)d_out;
    char* ws = (char*)d_ws;

    // ws layout (bytes). ao16 aliases wqkv16 (dead after gemm_qkv).
    double*    scal   = (double*)(ws + 0);
    int*       win    = (int*)(ws + 64);
    float*     xmean  = (float*)(ws + 128);
    float*     hidden = (float*)(ws + 16640);
    float2*    cstab  = (float2*)(ws + 32768);       // 2 MB
    _Float16*  x16    = (_Float16*)(ws + 4194304);   // 16.8 MB
    _Float16*  wqkv16 = (_Float16*)(ws + 20971520);  // 25.2 MB
    _Float16*  ao16   = (_Float16*)(ws + 20971520);  // alias
    _Float16*  v16t   = (_Float16*)(ws + 46137344);  // 16.8 MB
    _Float16*  q16    = (_Float16*)(ws + 62914560);  // 16.8 MB
    _Float16*  k16    = (_Float16*)(ws + 79691776);  // 16.8 MB
    _Float16*  wout16 = (_Float16*)(ws + 96468992);  // 8.4 MB

    hipMemsetAsync(d_ws, 0, 32768, stream);

    rope_table<<<dim3(S_LEN), dim3(HDIM), 0, stream>>>(cstab);
    col_reduce<<<dim3(2, 64, 2), dim3(256), 0, stream>>>(x, xmean, scal, x16);
    hidden_kernel<<<dim3(512, 2), dim3(256), 0, stream>>>(xmean, w_c1, hidden);
    window_kernel<<<dim3(1), dim3(512), 0, stream>>>(hidden, w_c2, scal, win);

    cvt_weights<<<dim3((NQKV4 + NOUT4) / 256), dim3(256), 0, stream>>>(
        w_qkv, w_out, wqkv16, wout16);

    gemm_qkv_f16<<<dim3(48, 32), dim3(256), 0, stream>>>(x16, wqkv16, q16, k16, v16t, cstab);
    attn_mfma<<<dim3(32, HEADS, 2), dim3(256), 0, stream>>>(q16, k16, v16t, ao16, win);
    gemm_out_f16<<<dim3(16, 32), dim3(256), 0, stream>>>(ao16, wout16, out);
}